// Round 13
// baseline (9294.559 us; speedup 1.0000x reference)
//
#include <hip/hip_runtime.h>
#include <stdint.h>

typedef unsigned short u16;
typedef __attribute__((ext_vector_type(8))) short short8;
typedef __attribute__((ext_vector_type(4))) float f32x4;

#define MFMA16(a,b,c) __builtin_amdgcn_mfma_f32_16x16x32_bf16((a),(b),(c),0,0,0)
#define AT_LD(p)    __hip_atomic_load((p), __ATOMIC_RELAXED, __HIP_MEMORY_SCOPE_AGENT)
#define AT_LD64(p)  __hip_atomic_load((p), __ATOMIC_RELAXED, __HIP_MEMORY_SCOPE_AGENT)
#define AT_ST(p,v)  __hip_atomic_store((p), (v), __ATOMIC_RELAXED, __HIP_MEMORY_SCOPE_AGENT)

__device__ __forceinline__ float b2f(u16 u){
  union { uint32_t i; float f; } v; v.i = ((uint32_t)u) << 16; return v.f;
}
__device__ __forceinline__ u16 f2bf(float f){
  union { float f; uint32_t i; } v; v.f = f;
  uint32_t x = v.i;
  return (u16)((x + 0x7fffu + ((x >> 16) & 1u)) >> 16);
}
__device__ __forceinline__ float sigm(float x){ return 1.f/(1.f + __expf(-x)); }
__device__ __forceinline__ float tanh_f(float x){ float e = __expf(-2.f*x); return 2.f/(1.f+e) - 1.f; }

__device__ __forceinline__ void gbar_arrive(unsigned* flags, int my, unsigned target){
  __syncthreads();
  if (threadIdx.x == 0) AT_ST(&flags[my*32], target);
}
__device__ __forceinline__ void gbar_wait16(unsigned* flags, unsigned target){
  if (threadIdx.x < 16){
    while (AT_LD(&flags[threadIdx.x*32]) < target) {}
  }
  __syncthreads();
}

// in-register 4x4 transpose within each aligned 4-lane group.
__device__ __forceinline__ f32x4 xpose4(f32x4 a, int m){
  int b0 = m & 1, b1 = (m >> 1) & 1;
  float s01 = b0 ? a[0] : a[1];
  float s23 = b0 ? a[2] : a[3];
  float r01 = __shfl_xor(s01, 1);
  float r23 = __shfl_xor(s23, 1);
  float w0 = b0 ? r01 : a[0];
  float w1 = b0 ? a[1] : r01;
  float w2 = b0 ? r23 : a[2];
  float w3 = b0 ? a[3] : r23;
  float u02 = b1 ? w0 : w2;
  float u13 = b1 ? w1 : w3;
  float p02 = __shfl_xor(u02, 2);
  float p13 = __shfl_xor(u13, 2);
  f32x4 x;
  x[0] = b1 ? p02 : w0;
  x[1] = b1 ? p13 : w1;
  x[2] = b1 ? w2 : p02;
  x[3] = b1 ? w3 : p13;
  return x;
}

// stage full h (64x512 bf16) into swizzled LDS via u64 coherent loads.
__device__ __forceinline__ void stage_h512(const u16* hrd, u16* hs, int tid){
  const unsigned long long* h64 = (const unsigned long long*)hrd;
  #pragma unroll
  for (int cc=0; cc<8; ++cc){
    int S = cc*512 + tid;
    int row = S >> 6, s = S & 63;
    union { unsigned long long q[2]; short8 v; } pk;
    pk.q[0] = AT_LD64(h64 + (size_t)S*2);
    pk.q[1] = AT_LD64(h64 + (size_t)S*2 + 1);
    *(short8*)&hs[row*512 + ((s ^ (row&7))<<3)] = pk.v;
  }
}
__device__ __forceinline__ void stage_h256(const u16* hrd, u16* hs, int tid){
  const unsigned long long* h64 = (const unsigned long long*)hrd;
  #pragma unroll
  for (int cc=0; cc<16; ++cc){
    int S = cc*256 + tid;
    int row = S >> 6, s = S & 63;
    union { unsigned long long q[2]; short8 v; } pk;
    pk.q[0] = AT_LD64(h64 + (size_t)S*2);
    pk.q[1] = AT_LD64(h64 + (size_t)S*2 + 1);
    *(short8*)&hs[row*512 + ((s ^ (row&7))<<3)] = pk.v;
  }
}

__global__ void cvt_pad(const float* __restrict__ src, u16* __restrict__ dst,
                        int R, int sStride, int sOff, int Cd, int Ccopy){
  int i = blockIdx.x*256 + threadIdx.x;
  if (i >= R*Cd) return;
  int r = i / Cd, c = i % Cd;
  dst[i] = (c < Ccopy) ? f2bf(src[(size_t)r*sStride + sOff + c]) : (u16)0;
}

__global__ void padf(const float* __restrict__ src, float* __restrict__ dst, int R, int Cs, int Cd){
  int i = blockIdx.x*256 + threadIdx.x;
  if (i >= R*Cd) return;
  int r = i/Cd, c = i%Cd;
  dst[i] = (c < Cs) ? src[r*Cs + c] : 0.f;
}

// WmT[j*512+k] = bf16(Wm[k*1024 + 512 + j])
__global__ void wmT_kernel(const float* __restrict__ Wm, u16* __restrict__ dst){
  int idx = blockIdx.x*256 + threadIdx.x;
  if (idx >= 512*512) return;
  int j = idx >> 9, k = idx & 511;
  dst[idx] = f2bf(Wm[(size_t)k*1024 + 512 + j]);
}

// C = A(MxK,bf16) @ Bw(NxK,bf16)^T + bias(f32), f32 acc, mode-specific store
__global__ __launch_bounds__(256) void gemm_bt(
    const u16* __restrict__ A, int lda,
    const u16* __restrict__ Bw, int ldb,
    const float* __restrict__ bias,
    int M, int N, int K, int mode,
    void* __restrict__ o0, void* __restrict__ o1, void* __restrict__ o2, int ldo)
{
  if (mode == 3){
    int e = blockIdx.z;
    A    += (size_t)e * 64;
    Bw   += (size_t)e * 512 * 64;
    bias += (size_t)e * 512;
  }
  __shared__ u16 As[128*64];
  __shared__ u16 Bs[128*64];
  const int row0 = blockIdx.x * 128, col0 = blockIdx.y * 128;
  const int tid = threadIdx.x;
  const int l = tid & 63, w = tid >> 6;
  const int lr = l & 15, lk = l >> 4;
  const int wr = w >> 1, wc = w & 1;
  f32x4 acc[4][4];
  #pragma unroll
  for (int a=0;a<4;++a)
    #pragma unroll
    for (int b=0;b<4;++b) acc[a][b] = (f32x4){0.f,0.f,0.f,0.f};

  for (int k0 = 0; k0 < K; k0 += 64){
    #pragma unroll
    for (int s = 0; s < 4; ++s){
      int cid = s*256 + tid;
      int r = cid >> 3, ck = cid & 7;
      *(short8*)&As[r*64 + ck*8] = *(const short8*)&A[(size_t)(row0 + r)*lda + k0 + ck*8];
      *(short8*)&Bs[r*64 + ck*8] = *(const short8*)&Bw[(size_t)(col0 + r)*ldb + k0 + ck*8];
    }
    __syncthreads();
    #pragma unroll
    for (int kt = 0; kt < 2; ++kt){
      short8 af[4], bf[4];
      #pragma unroll
      for (int mt=0;mt<4;++mt) af[mt] = *(const short8*)&As[(wr*64 + mt*16 + lr)*64 + kt*32 + lk*8];
      #pragma unroll
      for (int nt=0;nt<4;++nt) bf[nt] = *(const short8*)&Bs[(wc*64 + nt*16 + lr)*64 + kt*32 + lk*8];
      #pragma unroll
      for (int mt=0;mt<4;++mt)
        #pragma unroll
        for (int nt=0;nt<4;++nt) acc[mt][nt] = MFMA16(af[mt], bf[nt], acc[mt][nt]);
    }
    __syncthreads();
  }

  #pragma unroll
  for (int mt=0;mt<4;++mt){
    #pragma unroll
    for (int nt=0;nt<4;++nt){
      int col = col0 + wc*64 + nt*16 + lr;
      float bv = bias[col];
      #pragma unroll
      for (int i=0;i<4;++i){
        int r = row0 + wr*64 + mt*16 + lk*4 + i;
        float v = acc[mt][nt][i] + bv;
        if (mode == 0){                 // r = b*512+t ; [t][b][1536] bf16 (col<1536 only when N=1536)
          int bb = r >> 9, t = r & 511;
          size_t ro = ((size_t)t*64 + bb)*1536;
          if (col < 1536) ((u16*)o0)[ro + col] = f2bf(v);
          else            ((u16*)o1)[ro + col - 1536] = f2bf(v);
        } else if (mode == 1){
          ((u16*)o0)[(size_t)r*ldo + col] = f2bf(v);
        } else if (mode == 2){
          int t = r >> 6, bb = r & 63;
          if (t < 511){
            size_t orow = (size_t)bb*511 + t;
            if (col < 512){
              ((float*)o0)[orow*528 + col] = v;
              ((u16*)o2)[orow*512 + col] = f2bf(v);
            } else if (col < 528){
              ((float*)o0)[orow*528 + col] = v;
            } else if (col == 528){
              ((float*)o1)[orow] = v;
            }
          }
        } else if (mode == 3){
          if (r < M && col < 500) ((float*)o0)[(size_t)(blockIdx.z)*16352000ull + (size_t)r*500 + col] = v;
        } else {
          if (r < M) ((float*)o0)[(size_t)r*ldo + col] = v;
        }
      }
    }
  }
}

// Merged: blocks 0..15 = encoder recurrence (16 WGs x 512 thr, r10-proven);
// blocks 16.. = XG0-half GEMM (x2h0 = Xp @ W0x^T + b0x), tid<256 active, overlapped under enc.
__global__ __launch_bounds__(512,2) void encg_kernel(
    const u16* __restrict__ Whh, const float* __restrict__ bhh,
    const u16* __restrict__ XGE, const int* __restrict__ seqs,
    u16* __restrict__ hd, float* __restrict__ lasth,
    unsigned* __restrict__ flags,
    const u16* __restrict__ Xp, const u16* __restrict__ Wcx,
    const float* __restrict__ biasx, u16* __restrict__ XG0)
{
  __shared__ u16 shbuf[64*512];
  const int tid = threadIdx.x;
  if (blockIdx.x < 16){
    u16* hs = shbuf;
    const int l = tid & 63, w = tid >> 6;
    const int lr = l & 15, lk = l >> 4;
    const int m = l & 3;
    const int gw = blockIdx.x*8 + w;
    const int hcol = gw*4 + (lr >> 2);

    const int msel = (m == 3) ? 0 : m;
    const u16* wbase = Whh + ((size_t)(msel*512) + hcol)*512;
    short8 bw[16];
    #pragma unroll
    for (int kt=0;kt<16;++kt) bw[kt] = *(const short8*)&wbase[kt*32 + lk*8];

    const float bhr = bhh[hcol], bhz = bhh[512+hcol], bhn = bhh[1024+hcol];
    int rowc[4]; int len[4]; float hreg[4];
    float xr[4], xz[4], xn[4];
    #pragma unroll
    for (int c=0;c<4;++c){
      rowc[c] = c*16 + lk*4 + m;
      len[c] = seqs[rowc[c]];
      hreg[c] = 0.f;
      const u16* p = XGE + (size_t)rowc[c]*1536;
      xr[c]=b2f(p[hcol]); xz[c]=b2f(p[512+hcol]); xn[c]=b2f(p[1024+hcol]);
    }

    for (int t=0; t<512; ++t){
      const u16* hrd = hd + (t & 1)*32768;
      u16*       hwr = hd + ((t & 1)^1)*32768;
      stage_h512(hrd, hs, tid);
      __syncthreads();
      #pragma unroll
      for (int c=0;c<4;++c){
        short8 af[16];
        #pragma unroll
        for (int kt=0;kt<16;++kt)
          af[kt] = *(const short8*)&hs[(c*16+lr)*512 + (((kt*4+lk) ^ (lr&7))<<3)];
        f32x4 acc = (f32x4){0.f,0.f,0.f,0.f};
        #pragma unroll
        for (int kt=0;kt<16;++kt) acc = MFMA16(af[kt], bw[kt], acc);
        f32x4 x = xpose4(acc, m);
        float rg = sigm(xr[c] + x[0] + bhr);
        float zg = sigm(xz[c] + x[1] + bhz);
        float ng = tanh_f(xn[c] + rg*(x[2] + bhn));
        float hv = (1.f - zg)*ng + zg*hreg[c];
        hreg[c] = hv;
        AT_ST(&hwr[rowc[c]*512 + hcol], f2bf(hv));
        if (t == len[c]-1) lasth[rowc[c]*512 + hcol] = hv;
      }
      if (t < 511){
        gbar_arrive(flags, blockIdx.x, (unsigned)(t+1));
        const u16* p0 = XGE + (size_t)(t+1)*98304;
        #pragma unroll
        for (int c=0;c<4;++c){
          const u16* p = p0 + (size_t)rowc[c]*1536;
          xr[c]=b2f(p[hcol]); xz[c]=b2f(p[512+hcol]); xn[c]=b2f(p[1024+hcol]);
        }
        gbar_wait16(flags, (unsigned)(t+1));
      }
    }
  } else {
    // XG0 gemm: grid 256 x 12 mapped onto blockIdx.x-16
    const int g = blockIdx.x - 16;
    const int row0 = (g & 255)*128, col0 = (g >> 8)*128;
    const bool act = tid < 256;
    u16* As = shbuf;
    u16* Bs = shbuf + 8192;
    const int l = tid & 63, w = tid >> 6;
    const int lr = l & 15, lk = l >> 4;
    const int wr = (w & 3) >> 1, wc = w & 1;
    f32x4 acc[4][4];
    #pragma unroll
    for (int a=0;a<4;++a)
      #pragma unroll
      for (int b=0;b<4;++b) acc[a][b] = (f32x4){0.f,0.f,0.f,0.f};

    for (int k0 = 0; k0 < 576; k0 += 64){
      if (act){
        #pragma unroll
        for (int s = 0; s < 4; ++s){
          int cid = s*256 + tid;
          int r = cid >> 3, ck = cid & 7;
          *(short8*)&As[r*64 + ck*8] = *(const short8*)&Xp[(size_t)(row0 + r)*576 + k0 + ck*8];
          *(short8*)&Bs[r*64 + ck*8] = *(const short8*)&Wcx[(size_t)(col0 + r)*576 + k0 + ck*8];
        }
      }
      __syncthreads();
      if (act){
        #pragma unroll
        for (int kt = 0; kt < 2; ++kt){
          short8 af[4], bf[4];
          #pragma unroll
          for (int mt=0;mt<4;++mt) af[mt] = *(const short8*)&As[(wr*64 + mt*16 + lr)*64 + kt*32 + lk*8];
          #pragma unroll
          for (int nt=0;nt<4;++nt) bf[nt] = *(const short8*)&Bs[(wc*64 + nt*16 + lr)*64 + kt*32 + lk*8];
          #pragma unroll
          for (int mt=0;mt<4;++mt)
            #pragma unroll
            for (int nt=0;nt<4;++nt) acc[mt][nt] = MFMA16(af[mt], bf[nt], acc[mt][nt]);
        }
      }
      __syncthreads();
    }
    if (act){
      #pragma unroll
      for (int mt=0;mt<4;++mt){
        #pragma unroll
        for (int nt=0;nt<4;++nt){
          int col = col0 + wc*64 + nt*16 + lr;
          float bv = biasx[col];
          #pragma unroll
          for (int i=0;i<4;++i){
            int r = row0 + wr*64 + mt*16 + lk*4 + i;
            int bb = r >> 9, t = r & 511;
            XG0[((size_t)t*64 + bb)*1536 + col] = f2bf(acc[mt][nt][i] + bv);
          }
        }
      }
    }
  }
}

// Fused decoder: 48 WGs x 256 thr. WG<32 = role0 (chain0 + xg1); WG 32..47 = role1
// (chain1, 8 hcols/wave, 2-phase lag). Skewed barrier; xgb triple-buffered.
__global__ __launch_bounds__(256,1) void decf_kernel(
    const u16* __restrict__ Wm0, const u16* __restrict__ Wcp0,
    const float* __restrict__ ghm0v, const float* __restrict__ ghW0v,
    const u16* __restrict__ W1xc, const float* __restrict__ b1xv,
    const u16* __restrict__ Wm1, const u16* __restrict__ Wcp1,
    const float* __restrict__ ghm1v, const float* __restrict__ ghW1v,
    const u16* __restrict__ XG0,
    u16* __restrict__ h0d, u16* __restrict__ h1d,
    u16* __restrict__ xgb,     // 3 x 64x1536 bf16
    u16* __restrict__ Hall,
    unsigned* __restrict__ flags)
{
  __shared__ u16 hs[64*512];
  const int tid = threadIdx.x;
  const int l = tid & 63, w = tid >> 6;
  const int lr = l & 15, lk = l >> 4;
  const int m = l & 3;

  int rowc[4];
  #pragma unroll
  for (int c=0;c<4;++c) rowc[c] = c*16 + lk*4 + m;

  if (blockIdx.x < 32){
    // ---------------- role 0 ----------------
    const int gw = blockIdx.x*4 + w;
    const int hcol = gw*4 + (lr >> 2);
    const u16* wb = (m == 0) ? (Wm0 + (size_t)hcol*512)
                             : (Wcp0 + ((size_t)((m-1)*512) + hcol)*512);
    short8 bw[16];
    #pragma unroll
    for (int kt=0;kt<16;++kt) bw[kt] = *(const short8*)&wb[kt*32 + lk*8];

    const bool xact = (gw < 96);
    const int xcol0 = gw*16;
    const int cbase = xcol0 + (lr & ~3);
    short8 bwx[16];
    float bx0=0.f, bx1=0.f, bx2=0.f, bx3=0.f;
    if (xact){
      #pragma unroll
      for (int kt=0;kt<16;++kt) bwx[kt] = *(const short8*)&W1xc[(size_t)(xcol0+lr)*512 + kt*32 + lk*8];
      bx0 = b1xv[cbase]; bx1 = b1xv[cbase+1]; bx2 = b1xv[cbase+2]; bx3 = b1xv[cbase+3];
    }
    float ghmr[4], g0[4], g1[4], g2[4];
    float xr[4], xz[4], xn[4];
    #pragma unroll
    for (int c=0;c<4;++c){
      int row = rowc[c];
      ghmr[c] = ghm0v[row*512 + hcol];
      g0[c] = ghW0v[row*1536 + hcol];
      g1[c] = ghW0v[row*1536 + 512 + hcol];
      g2[c] = ghW0v[row*1536 + 1024 + hcol];
      const u16* p = XG0 + (size_t)row*1536;
      xr[c]=b2f(p[hcol]); xz[c]=b2f(p[512+hcol]); xn[c]=b2f(p[1024+hcol]);
    }

    for (int p=0; p<=513; ++p){
      if (p <= 512){
        stage_h256(h0d + (p&1)*32768, hs, tid);
        __syncthreads();
        u16* hwr = h0d + ((p&1)^1)*32768;
        u16* xw  = xgb + (size_t)((p+2)%3)*98304;   // (p-1)%3 == (p+2)%3
        #pragma unroll
        for (int c=0;c<4;++c){
          short8 af[16];
          #pragma unroll
          for (int kt=0;kt<16;++kt)
            af[kt] = *(const short8*)&hs[(c*16+lr)*512 + (((kt*4+lk) ^ (lr&7))<<3)];
          if (p <= 511){
            f32x4 ga = (f32x4){0.f,0.f,0.f,0.f};
            #pragma unroll
            for (int kt=0;kt<16;++kt) ga = MFMA16(af[kt], bw[kt], ga);
            f32x4 x = xpose4(ga, m);
            float hx = x[0] + ghmr[c];
            float rv = sigm(xr[c] + x[1] + g0[c]);
            float zv = sigm(xz[c] + x[2] + g1[c]);
            float nv = tanh_f(xn[c] + rv*(x[3] + g2[c]));
            float hv = zv*hx + (1.f - zv)*nv;
            AT_ST(&hwr[rowc[c]*512 + hcol], f2bf(hv));
          }
          if (p >= 1 && xact){
            f32x4 xa = (f32x4){0.f,0.f,0.f,0.f};
            #pragma unroll
            for (int kt=0;kt<16;++kt) xa = MFMA16(af[kt], bwx[kt], xa);
            f32x4 xv = xpose4(xa, m);
            unsigned lo = (unsigned)f2bf(xv[0]+bx0) | ((unsigned)f2bf(xv[1]+bx1) << 16);
            unsigned hi = (unsigned)f2bf(xv[2]+bx2) | ((unsigned)f2bf(xv[3]+bx3) << 16);
            unsigned long long v64 = (unsigned long long)lo | ((unsigned long long)hi << 32);
            __hip_atomic_store((unsigned long long*)&xw[(size_t)rowc[c]*1536 + cbase], v64,
                               __ATOMIC_RELAXED, __HIP_MEMORY_SCOPE_AGENT);
          }
        }
      }
      if (p < 513){
        __syncthreads();
        if (tid == 0) AT_ST(&flags[blockIdx.x*32], (unsigned)(p+1));
        if (p <= 510){
          const u16* xgn = XG0 + (size_t)(p+1)*98304;
          #pragma unroll
          for (int c=0;c<4;++c){
            const u16* q = xgn + (size_t)rowc[c]*1536;
            xr[c]=b2f(q[hcol]); xz[c]=b2f(q[512+hcol]); xn[c]=b2f(q[1024+hcol]);
          }
        }
        if (tid < 32){
          while (AT_LD(&flags[tid*32]) < (unsigned)(p+1)) {}
        } else if (tid < 48){
          while (AT_LD(&flags[tid*32]) < (unsigned)p) {}
        }
        __syncthreads();
      }
    }
  } else {
    // ---------------- role 1: 16 WGs, 8 hcols/wave ----------------
    const int gw = (blockIdx.x - 32)*4 + w;      // 0..63
    int hc2[2];
    hc2[0] = gw*8 + (lr >> 2);
    hc2[1] = gw*8 + 4 + (lr >> 2);
    short8 bw1[2][16];
    #pragma unroll
    for (int h=0;h<2;++h){
      const u16* wb = (m == 0) ? (Wm1 + (size_t)hc2[h]*512)
                               : (Wcp1 + ((size_t)((m-1)*512) + hc2[h])*512);
      #pragma unroll
      for (int kt=0;kt<16;++kt) bw1[h][kt] = *(const short8*)&wb[kt*32 + lk*8];
    }
    float ghmr[2][4], g0[2][4], g1[2][4], g2[2][4];
    #pragma unroll
    for (int h=0;h<2;++h)
      #pragma unroll
      for (int c=0;c<4;++c){
        int row = rowc[c];
        ghmr[h][c] = ghm1v[row*512 + hc2[h]];
        g0[h][c] = ghW1v[row*1536 + hc2[h]];
        g1[h][c] = ghW1v[row*1536 + 512 + hc2[h]];
        g2[h][c] = ghW1v[row*1536 + 1024 + hc2[h]];
      }

    for (int p=0; p<=513; ++p){
      if (p >= 2){
        const int t = p - 2;
        const u16* xb = xgb + (size_t)(t%3)*98304;
        float xr[2][4], xz[2][4], xn[2][4];
        #pragma unroll
        for (int h=0;h<2;++h)
          #pragma unroll
          for (int c=0;c<4;++c){
            xr[h][c] = b2f(AT_LD(&xb[(size_t)rowc[c]*1536 + hc2[h]]));
            xz[h][c] = b2f(AT_LD(&xb[(size_t)rowc[c]*1536 + 512 + hc2[h]]));
            xn[h][c] = b2f(AT_LD(&xb[(size_t)rowc[c]*1536 + 1024 + hc2[h]]));
          }
        stage_h256(h1d + (t&1)*32768, hs, tid);
        __syncthreads();
        u16* hwr = h1d + ((t&1)^1)*32768;
        u16* Ht  = Hall + (size_t)t*32768;
        #pragma unroll
        for (int c=0;c<4;++c){
          short8 af[16];
          #pragma unroll
          for (int kt=0;kt<16;++kt)
            af[kt] = *(const short8*)&hs[(c*16+lr)*512 + (((kt*4+lk) ^ (lr&7))<<3)];
          #pragma unroll
          for (int h=0;h<2;++h){
            f32x4 ga = (f32x4){0.f,0.f,0.f,0.f};
            #pragma unroll
            for (int kt=0;kt<16;++kt) ga = MFMA16(af[kt], bw1[h][kt], ga);
            f32x4 x = xpose4(ga, m);
            float hx = x[0] + ghmr[h][c];
            float rv = sigm(xr[h][c] + x[1] + g0[h][c]);
            float zv = sigm(xz[h][c] + x[2] + g1[h][c]);
            float nv = tanh_f(xn[h][c] + rv*(x[3] + g2[h][c]));
            float hv = zv*hx + (1.f - zv)*nv;
            u16 hb = f2bf(hv);
            AT_ST(&hwr[rowc[c]*512 + hc2[h]], hb);
            Ht[rowc[c]*512 + hc2[h]] = hb;
          }
        }
      }
      if (p < 513){
        __syncthreads();
        if (tid == 0) AT_ST(&flags[blockIdx.x*32], (unsigned)(p+1));
        if (tid < 48){
          while (AT_LD(&flags[tid*32]) < (unsigned)(p+1)) {}
        }
        __syncthreads();
      }
    }
  }
}

// ghm{0,1}[b][j] = b{0,1}m[j] + sum_k lasth[b][k]*W{0,1}m[j][k]; also bf16 padded copy
__global__ void ghm_kernel(const float* __restrict__ lasth,
                           const float* __restrict__ W0m, const float* __restrict__ b0m,
                           const float* __restrict__ W1m, const float* __restrict__ b1m,
                           float* __restrict__ ghm0, float* __restrict__ ghm1,
                           u16* __restrict__ ghmP)
{
  int idx = blockIdx.x*256 + threadIdx.x;
  int chain = idx >> 15;
  int j = (idx >> 6) & 511;
  int b = idx & 63;
  const float* Wm = chain ? W1m : W0m;
  const float* bm = chain ? b1m : b0m;
  float s = 0.f;
  for (int k=0;k<512;++k) s += lasth[b*512 + k] * Wm[(size_t)j*1024 + k];
  float v = s + bm[j];
  (chain ? ghm1 : ghm0)[b*512 + j] = v;
  ghmP[(size_t)chain*65536 + b*512 + j] = f2bf(v);
}

extern "C" void kernel_launch(void* const* d_in, const int* in_sizes, int n_in,
                              void* d_out, int out_size, void* d_ws, size_t ws_size,
                              hipStream_t stream)
{
  const float* x    = (const float*)d_in[0];
  const float* Wih  = (const float*)d_in[1];
  const float* Whh  = (const float*)d_in[2];
  const float* bih  = (const float*)d_in[3];
  const float* bhh  = (const float*)d_in[4];
  const float* W0x  = (const float*)d_in[5];
  const float* b0x  = (const float*)d_in[6];
  const float* W0h  = (const float*)d_in[7];
  const float* b0h  = (const float*)d_in[8];
  const float* W0m  = (const float*)d_in[9];
  const float* b0m  = (const float*)d_in[10];
  const float* W1x  = (const float*)d_in[11];
  const float* b1x  = (const float*)d_in[12];
  const float* W1h  = (const float*)d_in[13];
  const float* b1h  = (const float*)d_in[14];
  const float* W1m  = (const float*)d_in[15];
  const float* b1m  = (const float*)d_in[16];
  const float* Wout = (const float*)d_in[17];
  const float* bout = (const float*)d_in[18];
  const float* Wdel = (const float*)d_in[19];
  const float* bdel = (const float*)d_in[20];
  const float* Wemb = (const float*)d_in[21];
  const float* bemb = (const float*)d_in[22];
  const int*   seqs = (const int*)d_in[23];
  float* out = (float*)d_out;

  const size_t OFF_DELTA = 17267712ull;
  const size_t OFF_EMB   = 17300416ull;
  const size_t OFF_LASTH = 148116416ull;

  uint8_t* ws = (uint8_t*)d_ws;
  size_t off = 0;
  auto alloc = [&](size_t bytes)->size_t{ size_t p = off; off += (bytes + 511) & ~(size_t)511; return p; };
  u16*   XGE  = (u16*)(ws + alloc(32768ull*1536*2));     // xg_enc; head aliases WmT before GEMM1
  u16*   WmT0 = XGE;
  u16*   WmT1 = XGE + 262144;
  u16*   XG0  = (u16*)(ws + alloc(32768ull*1536*2));     // x2h0; Ob aliases head after decf
  u16*   Ob   = XG0;
  uint8_t* reg3 = ws + alloc(2ull*33554432);             // Xp (pre) aliases H1 (post)
  u16*   Xp   = (u16*)reg3;
  u16*   H1   = (u16*)reg3;
  u16*   Wc   = (u16*)(ws + alloc(3072ull*576*2));
  u16*   Whc  = (u16*)(ws + alloc(1536ull*512*2));
  u16*   W0hc = (u16*)(ws + alloc(1536ull*512*2));
  u16*   W1hc = (u16*)(ws + alloc(1536ull*512*2));
  u16*   W1xc = (u16*)(ws + alloc(1536ull*512*2));
  u16*   Wm0c = (u16*)(ws + alloc(512ull*512*2));
  u16*   Wm1c = (u16*)(ws + alloc(512ull*512*2));
  u16*   Wcp0 = (u16*)(ws + alloc(1536ull*512*2));
  u16*   Wcp1 = (u16*)(ws + alloc(1536ull*512*2));
  u16*   Woc  = (u16*)(ws + alloc(640ull*512*2));
  u16*   Wep  = (u16*)(ws + alloc(8ull*512*64*2));
  u16*   ghmP = (u16*)(ws + alloc(2ull*128*512*2));
  u16*   xgb  = (u16*)(ws + alloc(3ull*64*1536*2));      // xg1 exchange, triple buffered
  float* bc1  = (float*)(ws + alloc(3072*4));
  float* bc3  = (float*)(ws + alloc(640*4));
  float* bep  = (float*)(ws + alloc(8*512*4));
  float* bzero= (float*)(ws + alloc(512*4));
  float* ghm0 = (float*)(ws + alloc(64*512*4));
  float* ghm1 = (float*)(ws + alloc(64*512*4));
  float* ghW0 = (float*)(ws + alloc(64*1536*4));
  float* ghW1 = (float*)(ws + alloc(64*1536*4));
  size_t state_off = off;
  u16*   henc = (u16*)(ws + alloc(2*64*512*2));
  u16*   h0d  = (u16*)(ws + alloc(2*64*512*2));
  u16*   h1d  = (u16*)(ws + alloc(2*64*512*2));
  unsigned* bars = (unsigned*)(ws + alloc(16384));       // enc: bars, decf: bars+1024
  size_t state_bytes = off - state_off;
  if (ws_size < off) return;

  hipMemsetAsync(ws + state_off, 0, state_bytes, stream);
  hipMemsetAsync(Woc, 0, 640ull*512*2, stream);
  hipMemsetAsync(Wep, 0, 8ull*512*64*2, stream);
  hipMemsetAsync(ghmP, 0, 2ull*128*512*2, stream);
  hipMemsetAsync(bc3, 0, 640*4, stream);
  hipMemsetAsync(bzero, 0, 512*4, stream);

  hipMemcpyAsync(bc1,        bih,  1536*4, hipMemcpyDeviceToDevice, stream);
  hipMemcpyAsync(bc1 + 1536, b0x,  1536*4, hipMemcpyDeviceToDevice, stream);
  hipMemcpyAsync(bc3,        bout, 528*4,  hipMemcpyDeviceToDevice, stream);
  hipMemcpyAsync(bc3 + 528,  bdel, 4,      hipMemcpyDeviceToDevice, stream);

  auto CV = [&](const float* s, u16* d, int R, int sStride, int sOff, int Cd, int Ccopy){
    int total = R*Cd; int gb = (total + 255)/256;
    cvt_pad<<<dim3(gb), dim3(256), 0, stream>>>(s, d, R, sStride, sOff, Cd, Ccopy);
  };
  CV(x,    Xp, 32768, 528, 0, 576, 528);
  CV(Wih,  Wc,              1536, 528, 0, 576, 528);
  CV(W0x,  Wc + 1536ull*576,1536, 528, 0, 576, 528);
  CV(Whh,  Whc,  1536, 512, 0, 512, 512);
  CV(W0h,  W0hc, 1536, 512, 0, 512, 512);
  CV(W1h,  W1hc, 1536, 512, 0, 512, 512);
  CV(W1x,  W1xc, 1536, 512, 0, 512, 512);
  CV(W0m,  Wm0c, 512, 1024, 512, 512, 512);
  CV(W1m,  Wm1c, 512, 1024, 512, 512, 512);
  CV(Wout, Woc,              528, 512, 0, 512, 512);
  CV(Wdel, Woc + 528ull*512, 1,   512, 0, 512, 512);
  for (int e=0;e<8;++e) CV(Wemb + (size_t)e*32000, Wep + (size_t)e*32768, 500, 64, 0, 64, 64);
  {
    int gb = (8*512 + 255)/256;
    padf<<<dim3(gb), dim3(256), 0, stream>>>(bemb, bep, 8, 500, 512);
  }
  wmT_kernel<<<dim3(1024), dim3(256), 0, stream>>>(W0m, WmT0);
  wmT_kernel<<<dim3(1024), dim3(256), 0, stream>>>(W1m, WmT1);

  // Wcomp = Wh @ Wmh (bf16), before GEMM1a overwrites XGE (WmT alias)
  gemm_bt<<<dim3(12,4), dim3(256), 0, stream>>>(W0hc, 512, WmT0, 512, bzero,
      1536, 512, 512, 1, Wcp0, nullptr, nullptr, 512);
  gemm_bt<<<dim3(12,4), dim3(256), 0, stream>>>(W1hc, 512, WmT1, 512, bzero,
      1536, 512, 512, 1, Wcp1, nullptr, nullptr, 512);

  // GEMM1a: xg_enc = Xp @ Wih^T + bih (XGE half only)
  gemm_bt<<<dim3(256,12), dim3(256), 0, stream>>>(Xp, 576, Wc, 576, bc1,
      32768, 1536, 576, 0, XGE, nullptr, nullptr, 0);
  // encoder recurrence + overlapped XG0-half GEMM (blocks 16..3087)
  encg_kernel<<<dim3(16 + 3072), dim3(512), 0, stream>>>(Whc, bhh, XGE, seqs,
      henc, out + OFF_LASTH, bars + 0,
      Xp, Wc + 1536ull*576, bc1 + 1536, XG0);
  // ghm0/ghm1
  ghm_kernel<<<dim3(256), dim3(256), 0, stream>>>(out + OFF_LASTH, W0m, b0m, W1m, b1m,
      ghm0, ghm1, ghmP);
  // ghW{0,1} = ghm @ Wh^T + bh
  gemm_bt<<<dim3(1,12), dim3(256), 0, stream>>>(ghmP, 512, W0hc, 512, b0h,
      64, 1536, 512, 5, ghW0, nullptr, nullptr, 1536);
  gemm_bt<<<dim3(1,12), dim3(256), 0, stream>>>(ghmP + 65536, 512, W1hc, 512, b1h,
      64, 1536, 512, 5, ghW1, nullptr, nullptr, 1536);
  // fused decoder (48 WGs x 256 threads)
  decf_kernel<<<dim3(48), dim3(256), 0, stream>>>(
      Wm0c, Wcp0, ghm0, ghW0, W1xc, b1x,
      Wm1c, Wcp1, ghm1, ghW1,
      XG0, h0d, h1d, xgb, H1, bars + 1024);
  // GEMM3: out (f32) + pred_delta (f32) + Ob (bf16)
  gemm_bt<<<dim3(256,5), dim3(256), 0, stream>>>(H1, 512, Woc, 512, bc3,
      32768, 640, 512, 2, out, out + OFF_DELTA, Ob, 0);
  // GEMM4: emb logits
  gemm_bt<<<dim3(256,4,8), dim3(256), 0, stream>>>(Ob, 512, Wep, 64, bep,
      32704, 512, 64, 3, out + OFF_EMB, nullptr, nullptr, 0);
}

// Round 14
// 8183.757 us; speedup vs baseline: 1.1357x; 1.1357x over previous
//
#include <hip/hip_runtime.h>
#include <stdint.h>

typedef unsigned short u16;
typedef __attribute__((ext_vector_type(8))) short short8;
typedef __attribute__((ext_vector_type(4))) float f32x4;

#define MFMA16(a,b,c) __builtin_amdgcn_mfma_f32_16x16x32_bf16((a),(b),(c),0,0,0)
#define AT_LD(p)    __hip_atomic_load((p), __ATOMIC_RELAXED, __HIP_MEMORY_SCOPE_AGENT)
#define AT_LD64(p)  __hip_atomic_load((p), __ATOMIC_RELAXED, __HIP_MEMORY_SCOPE_AGENT)
#define AT_ST(p,v)  __hip_atomic_store((p), (v), __ATOMIC_RELAXED, __HIP_MEMORY_SCOPE_AGENT)

__device__ __forceinline__ float b2f(u16 u){
  union { uint32_t i; float f; } v; v.i = ((uint32_t)u) << 16; return v.f;
}
__device__ __forceinline__ u16 f2bf(float f){
  union { float f; uint32_t i; } v; v.f = f;
  uint32_t x = v.i;
  return (u16)((x + 0x7fffu + ((x >> 16) & 1u)) >> 16);
}
__device__ __forceinline__ float sigm(float x){ return 1.f/(1.f + __expf(-x)); }
__device__ __forceinline__ float tanh_f(float x){ float e = __expf(-2.f*x); return 2.f/(1.f+e) - 1.f; }

__device__ __forceinline__ void gbar_arrive(unsigned* flags, int my, unsigned target){
  __syncthreads();
  if (threadIdx.x == 0) AT_ST(&flags[my*32], target);
}
__device__ __forceinline__ void gbar_wait16(unsigned* flags, unsigned target){
  if (threadIdx.x < 16){
    while (AT_LD(&flags[threadIdx.x*32]) < target) {}
  }
  __syncthreads();
}

// in-register 4x4 transpose within each aligned 4-lane group.
__device__ __forceinline__ f32x4 xpose4(f32x4 a, int m){
  int b0 = m & 1, b1 = (m >> 1) & 1;
  float s01 = b0 ? a[0] : a[1];
  float s23 = b0 ? a[2] : a[3];
  float r01 = __shfl_xor(s01, 1);
  float r23 = __shfl_xor(s23, 1);
  float w0 = b0 ? r01 : a[0];
  float w1 = b0 ? a[1] : r01;
  float w2 = b0 ? r23 : a[2];
  float w3 = b0 ? a[3] : r23;
  float u02 = b1 ? w0 : w2;
  float u13 = b1 ? w1 : w3;
  float p02 = __shfl_xor(u02, 2);
  float p13 = __shfl_xor(u13, 2);
  f32x4 x;
  x[0] = b1 ? p02 : w0;
  x[1] = b1 ? p13 : w1;
  x[2] = b1 ? w2 : p02;
  x[3] = b1 ? w3 : p13;
  return x;
}

// stage full h (64x512 bf16) into swizzled LDS via u64 coherent loads.
__device__ __forceinline__ void stage_h512(const u16* hrd, u16* hs, int tid){
  const unsigned long long* h64 = (const unsigned long long*)hrd;
  #pragma unroll
  for (int cc=0; cc<8; ++cc){
    int S = cc*512 + tid;
    int row = S >> 6, s = S & 63;
    union { unsigned long long q[2]; short8 v; } pk;
    pk.q[0] = AT_LD64(h64 + (size_t)S*2);
    pk.q[1] = AT_LD64(h64 + (size_t)S*2 + 1);
    *(short8*)&hs[row*512 + ((s ^ (row&7))<<3)] = pk.v;
  }
}
__device__ __forceinline__ void stage_h256(const u16* hrd, u16* hs, int tid){
  const unsigned long long* h64 = (const unsigned long long*)hrd;
  #pragma unroll
  for (int cc=0; cc<16; ++cc){
    int S = cc*256 + tid;
    int row = S >> 6, s = S & 63;
    union { unsigned long long q[2]; short8 v; } pk;
    pk.q[0] = AT_LD64(h64 + (size_t)S*2);
    pk.q[1] = AT_LD64(h64 + (size_t)S*2 + 1);
    *(short8*)&hs[row*512 + ((s ^ (row&7))<<3)] = pk.v;
  }
}

__global__ void cvt_pad(const float* __restrict__ src, u16* __restrict__ dst,
                        int R, int sStride, int sOff, int Cd, int Ccopy){
  int i = blockIdx.x*256 + threadIdx.x;
  if (i >= R*Cd) return;
  int r = i / Cd, c = i % Cd;
  dst[i] = (c < Ccopy) ? f2bf(src[(size_t)r*sStride + sOff + c]) : (u16)0;
}

__global__ void padf(const float* __restrict__ src, float* __restrict__ dst, int R, int Cs, int Cd){
  int i = blockIdx.x*256 + threadIdx.x;
  if (i >= R*Cd) return;
  int r = i/Cd, c = i%Cd;
  dst[i] = (c < Cs) ? src[r*Cs + c] : 0.f;
}

// WmT[j*512+k] = bf16(Wm[k*1024 + 512 + j])
__global__ void wmT_kernel(const float* __restrict__ Wm, u16* __restrict__ dst){
  int idx = blockIdx.x*256 + threadIdx.x;
  if (idx >= 512*512) return;
  int j = idx >> 9, k = idx & 511;
  dst[idx] = f2bf(Wm[(size_t)k*1024 + 512 + j]);
}

// C = A(MxK,bf16) @ Bw(NxK,bf16)^T + bias(f32), f32 acc, mode-specific store
__global__ __launch_bounds__(256) void gemm_bt(
    const u16* __restrict__ A, int lda,
    const u16* __restrict__ Bw, int ldb,
    const float* __restrict__ bias,
    int M, int N, int K, int mode,
    void* __restrict__ o0, void* __restrict__ o1, void* __restrict__ o2, int ldo)
{
  if (mode == 3){
    int e = blockIdx.z;
    A    += (size_t)e * 64;
    Bw   += (size_t)e * 512 * 64;
    bias += (size_t)e * 512;
  }
  __shared__ u16 As[128*64];
  __shared__ u16 Bs[128*64];
  const int row0 = blockIdx.x * 128, col0 = blockIdx.y * 128;
  const int tid = threadIdx.x;
  const int l = tid & 63, w = tid >> 6;
  const int lr = l & 15, lk = l >> 4;
  const int wr = w >> 1, wc = w & 1;
  f32x4 acc[4][4];
  #pragma unroll
  for (int a=0;a<4;++a)
    #pragma unroll
    for (int b=0;b<4;++b) acc[a][b] = (f32x4){0.f,0.f,0.f,0.f};

  for (int k0 = 0; k0 < K; k0 += 64){
    #pragma unroll
    for (int s = 0; s < 4; ++s){
      int cid = s*256 + tid;
      int r = cid >> 3, ck = cid & 7;
      *(short8*)&As[r*64 + ck*8] = *(const short8*)&A[(size_t)(row0 + r)*lda + k0 + ck*8];
      *(short8*)&Bs[r*64 + ck*8] = *(const short8*)&Bw[(size_t)(col0 + r)*ldb + k0 + ck*8];
    }
    __syncthreads();
    #pragma unroll
    for (int kt = 0; kt < 2; ++kt){
      short8 af[4], bf[4];
      #pragma unroll
      for (int mt=0;mt<4;++mt) af[mt] = *(const short8*)&As[(wr*64 + mt*16 + lr)*64 + kt*32 + lk*8];
      #pragma unroll
      for (int nt=0;nt<4;++nt) bf[nt] = *(const short8*)&Bs[(wc*64 + nt*16 + lr)*64 + kt*32 + lk*8];
      #pragma unroll
      for (int mt=0;mt<4;++mt)
        #pragma unroll
        for (int nt=0;nt<4;++nt) acc[mt][nt] = MFMA16(af[mt], bf[nt], acc[mt][nt]);
    }
    __syncthreads();
  }

  #pragma unroll
  for (int mt=0;mt<4;++mt){
    #pragma unroll
    for (int nt=0;nt<4;++nt){
      int col = col0 + wc*64 + nt*16 + lr;
      float bv = bias[col];
      #pragma unroll
      for (int i=0;i<4;++i){
        int r = row0 + wr*64 + mt*16 + lk*4 + i;
        float v = acc[mt][nt][i] + bv;
        if (mode == 0){
          int bb = r >> 9, t = r & 511;
          size_t ro = ((size_t)t*64 + bb)*1536;
          if (col < 1536) ((u16*)o0)[ro + col] = f2bf(v);
          else            ((u16*)o1)[ro + col - 1536] = f2bf(v);
        } else if (mode == 1){
          ((u16*)o0)[(size_t)r*ldo + col] = f2bf(v);
        } else if (mode == 2){
          int t = r >> 6, bb = r & 63;
          if (t < 511){
            size_t orow = (size_t)bb*511 + t;
            if (col < 512){
              ((float*)o0)[orow*528 + col] = v;
              ((u16*)o2)[orow*512 + col] = f2bf(v);
            } else if (col < 528){
              ((float*)o0)[orow*528 + col] = v;
            } else if (col == 528){
              ((float*)o1)[orow] = v;
            }
          }
        } else if (mode == 3){
          if (r < M && col < 500) ((float*)o0)[(size_t)(blockIdx.z)*16352000ull + (size_t)r*500 + col] = v;
        } else {
          if (r < M) ((float*)o0)[(size_t)r*ldo + col] = v;
        }
      }
    }
  }
}

// Merged: blocks 0..15 = encoder recurrence (16 WGs x 512 thr);
// blocks 16.. = XG0-half GEMM (x2h0 = Xp @ W0x^T + b0x), tid<256 active, overlapped under enc.
__global__ __launch_bounds__(512,2) void encg_kernel(
    const u16* __restrict__ Whh, const float* __restrict__ bhh,
    const u16* __restrict__ XGE, const int* __restrict__ seqs,
    u16* __restrict__ hd, float* __restrict__ lasth,
    unsigned* __restrict__ flags,
    const u16* __restrict__ Xp, const u16* __restrict__ Wcx,
    const float* __restrict__ biasx, u16* __restrict__ XG0)
{
  __shared__ u16 shbuf[64*512];
  const int tid = threadIdx.x;
  if (blockIdx.x < 16){
    u16* hs = shbuf;
    const int l = tid & 63, w = tid >> 6;
    const int lr = l & 15, lk = l >> 4;
    const int m = l & 3;
    const int gw = blockIdx.x*8 + w;
    const int hcol = gw*4 + (lr >> 2);

    const int msel = (m == 3) ? 0 : m;
    const u16* wbase = Whh + ((size_t)(msel*512) + hcol)*512;
    short8 bw[16];
    #pragma unroll
    for (int kt=0;kt<16;++kt) bw[kt] = *(const short8*)&wbase[kt*32 + lk*8];

    const float bhr = bhh[hcol], bhz = bhh[512+hcol], bhn = bhh[1024+hcol];
    int rowc[4]; int len[4]; float hreg[4];
    float xr[4], xz[4], xn[4];
    #pragma unroll
    for (int c=0;c<4;++c){
      rowc[c] = c*16 + lk*4 + m;
      len[c] = seqs[rowc[c]];
      hreg[c] = 0.f;
      const u16* p = XGE + (size_t)rowc[c]*1536;
      xr[c]=b2f(p[hcol]); xz[c]=b2f(p[512+hcol]); xn[c]=b2f(p[1024+hcol]);
    }

    for (int t=0; t<512; ++t){
      const u16* hrd = hd + (t & 1)*32768;
      u16*       hwr = hd + ((t & 1)^1)*32768;
      stage_h512(hrd, hs, tid);
      __syncthreads();
      #pragma unroll
      for (int c=0;c<4;++c){
        short8 af[16];
        #pragma unroll
        for (int kt=0;kt<16;++kt)
          af[kt] = *(const short8*)&hs[(c*16+lr)*512 + (((kt*4+lk) ^ (lr&7))<<3)];
        f32x4 acc = (f32x4){0.f,0.f,0.f,0.f};
        #pragma unroll
        for (int kt=0;kt<16;++kt) acc = MFMA16(af[kt], bw[kt], acc);
        f32x4 x = xpose4(acc, m);
        float rg = sigm(xr[c] + x[0] + bhr);
        float zg = sigm(xz[c] + x[1] + bhz);
        float ng = tanh_f(xn[c] + rg*(x[2] + bhn));
        float hv = (1.f - zg)*ng + zg*hreg[c];
        hreg[c] = hv;
        AT_ST(&hwr[rowc[c]*512 + hcol], f2bf(hv));
        if (t == len[c]-1) lasth[rowc[c]*512 + hcol] = hv;
      }
      if (t < 511){
        gbar_arrive(flags, blockIdx.x, (unsigned)(t+1));
        const u16* p0 = XGE + (size_t)(t+1)*98304;
        #pragma unroll
        for (int c=0;c<4;++c){
          const u16* p = p0 + (size_t)rowc[c]*1536;
          xr[c]=b2f(p[hcol]); xz[c]=b2f(p[512+hcol]); xn[c]=b2f(p[1024+hcol]);
        }
        gbar_wait16(flags, (unsigned)(t+1));
      }
    }
  } else {
    const int g = blockIdx.x - 16;
    const int row0 = (g & 255)*128, col0 = (g >> 8)*128;
    const bool act = tid < 256;
    u16* As = shbuf;
    u16* Bs = shbuf + 8192;
    const int l = tid & 63, w = tid >> 6;
    const int lr = l & 15, lk = l >> 4;
    const int wr = (w & 3) >> 1, wc = w & 1;
    f32x4 acc[4][4];
    #pragma unroll
    for (int a=0;a<4;++a)
      #pragma unroll
      for (int b=0;b<4;++b) acc[a][b] = (f32x4){0.f,0.f,0.f,0.f};

    for (int k0 = 0; k0 < 576; k0 += 64){
      if (act){
        #pragma unroll
        for (int s = 0; s < 4; ++s){
          int cid = s*256 + tid;
          int r = cid >> 3, ck = cid & 7;
          *(short8*)&As[r*64 + ck*8] = *(const short8*)&Xp[(size_t)(row0 + r)*576 + k0 + ck*8];
          *(short8*)&Bs[r*64 + ck*8] = *(const short8*)&Wcx[(size_t)(col0 + r)*576 + k0 + ck*8];
        }
      }
      __syncthreads();
      if (act){
        #pragma unroll
        for (int kt = 0; kt < 2; ++kt){
          short8 af[4], bf[4];
          #pragma unroll
          for (int mt=0;mt<4;++mt) af[mt] = *(const short8*)&As[(wr*64 + mt*16 + lr)*64 + kt*32 + lk*8];
          #pragma unroll
          for (int nt=0;nt<4;++nt) bf[nt] = *(const short8*)&Bs[(wc*64 + nt*16 + lr)*64 + kt*32 + lk*8];
          #pragma unroll
          for (int mt=0;mt<4;++mt)
            #pragma unroll
            for (int nt=0;nt<4;++nt) acc[mt][nt] = MFMA16(af[mt], bf[nt], acc[mt][nt]);
        }
      }
      __syncthreads();
    }
    if (act){
      #pragma unroll
      for (int mt=0;mt<4;++mt){
        #pragma unroll
        for (int nt=0;nt<4;++nt){
          int col = col0 + wc*64 + nt*16 + lr;
          float bv = biasx[col];
          #pragma unroll
          for (int i=0;i<4;++i){
            int r = row0 + wr*64 + mt*16 + lk*4 + i;
            int bb = r >> 9, t = r & 511;
            XG0[((size_t)t*64 + bb)*1536 + col] = f2bf(acc[mt][nt][i] + bv);
          }
        }
      }
    }
  }
}

// Fused decoder (r12-proven): 64 WGs x 256 thr, skewed per-role barrier, xgb triple-buffered.
//   role0 (WG<32), phase p: stage h0d[p&1]; if p<=511 compute h0(p); if p>=1 xg1(p-1) -> xgb[(p+2)%3].
//     wait: flags0 >= p+1, flags1 >= p
//   role1 (WG>=32), phase p>=2: t=p-2; read xgb[t%3]; stage h1d[t&1]; compute h1(t).
//     wait: all 64 flags >= p+1
__global__ __launch_bounds__(256,1) void decf_kernel(
    const u16* __restrict__ Wm0, const u16* __restrict__ Wcp0,
    const float* __restrict__ ghm0v, const float* __restrict__ ghW0v,
    const u16* __restrict__ W1xc, const float* __restrict__ b1xv,
    const u16* __restrict__ Wm1, const u16* __restrict__ Wcp1,
    const float* __restrict__ ghm1v, const float* __restrict__ ghW1v,
    const u16* __restrict__ XG0,
    u16* __restrict__ h0d, u16* __restrict__ h1d,
    u16* __restrict__ xgb,     // 3 x 64x1536 bf16
    u16* __restrict__ Hall,
    unsigned* __restrict__ flags)
{
  __shared__ u16 hs[64*512];
  const int tid = threadIdx.x;
  const int l = tid & 63, w = tid >> 6;
  const int lr = l & 15, lk = l >> 4;
  const int m = l & 3;
  const int role1 = (blockIdx.x >= 32) ? 1 : 0;
  const int b = blockIdx.x & 31;
  const int gw = b*4 + w;
  const int hcol = gw*4 + (lr >> 2);

  const u16* Wm  = role1 ? Wm1  : Wm0;
  const u16* Wcp = role1 ? Wcp1 : Wcp0;
  const float* ghm = role1 ? ghm1v : ghm0v;
  const float* ghW = role1 ? ghW1v : ghW0v;

  const u16* wb = (m == 0) ? (Wm + (size_t)hcol*512)
                           : (Wcp + ((size_t)((m-1)*512) + hcol)*512);
  short8 bw[16];
  #pragma unroll
  for (int kt=0;kt<16;++kt) bw[kt] = *(const short8*)&wb[kt*32 + lk*8];

  const bool xact = (!role1) && (gw < 96);
  const int xcol0 = gw*16;
  const int cbase = xcol0 + (lr & ~3);
  short8 bwx[16];
  float bx0=0.f, bx1=0.f, bx2=0.f, bx3=0.f;
  if (xact){
    #pragma unroll
    for (int kt=0;kt<16;++kt) bwx[kt] = *(const short8*)&W1xc[(size_t)(xcol0+lr)*512 + kt*32 + lk*8];
    bx0 = b1xv[cbase]; bx1 = b1xv[cbase+1]; bx2 = b1xv[cbase+2]; bx3 = b1xv[cbase+3];
  }

  int rowc[4]; float ghmr[4], g0[4], g1[4], g2[4];
  #pragma unroll
  for (int c=0;c<4;++c){
    int row = c*16 + lk*4 + m; rowc[c] = row;
    ghmr[c] = ghm[row*512 + hcol];
    g0[c] = ghW[row*1536 + hcol];
    g1[c] = ghW[row*1536 + 512 + hcol];
    g2[c] = ghW[row*1536 + 1024 + hcol];
  }
  float xr[4], xz[4], xn[4];
  if (!role1){
    #pragma unroll
    for (int c=0;c<4;++c){
      const u16* p = XG0 + (size_t)rowc[c]*1536;
      xr[c]=b2f(p[hcol]); xz[c]=b2f(p[512+hcol]); xn[c]=b2f(p[1024+hcol]);
    }
  } else {
    #pragma unroll
    for (int c=0;c<4;++c){ xr[c]=0.f; xz[c]=0.f; xn[c]=0.f; }
  }

  for (int p=0; p<=513; ++p){
    if (!role1){
      if (p <= 512){
        const int sp = p & 1;
        stage_h256(h0d + sp*32768, hs, tid);
        __syncthreads();
        u16* hwr = h0d + (sp^1)*32768;
        #pragma unroll
        for (int c=0;c<4;++c){
          short8 af[16];
          #pragma unroll
          for (int kt=0;kt<16;++kt)
            af[kt] = *(const short8*)&hs[(c*16+lr)*512 + (((kt*4+lk) ^ (lr&7))<<3)];
          if (p <= 511){
            f32x4 ga = (f32x4){0.f,0.f,0.f,0.f};
            #pragma unroll
            for (int kt=0;kt<16;++kt) ga = MFMA16(af[kt], bw[kt], ga);
            f32x4 x = xpose4(ga, m);
            float hx = x[0] + ghmr[c];
            float rv = sigm(xr[c] + x[1] + g0[c]);
            float zv = sigm(xz[c] + x[2] + g1[c]);
            float nv = tanh_f(xn[c] + rv*(x[3] + g2[c]));
            float hv = zv*hx + (1.f - zv)*nv;
            AT_ST(&hwr[rowc[c]*512 + hcol], f2bf(hv));
          }
          if (p >= 1 && xact){
            u16* xw = xgb + (size_t)((p+2)%3)*98304;   // == (p-1)%3
            f32x4 xa = (f32x4){0.f,0.f,0.f,0.f};
            #pragma unroll
            for (int kt=0;kt<16;++kt) xa = MFMA16(af[kt], bwx[kt], xa);
            f32x4 xv = xpose4(xa, m);
            unsigned lo = (unsigned)f2bf(xv[0]+bx0) | ((unsigned)f2bf(xv[1]+bx1) << 16);
            unsigned hi = (unsigned)f2bf(xv[2]+bx2) | ((unsigned)f2bf(xv[3]+bx3) << 16);
            unsigned long long v64 = (unsigned long long)lo | ((unsigned long long)hi << 32);
            __hip_atomic_store((unsigned long long*)&xw[(size_t)rowc[c]*1536 + cbase], v64,
                               __ATOMIC_RELAXED, __HIP_MEMORY_SCOPE_AGENT);
          }
        }
      }
    } else {
      if (p >= 2){
        const int t = p - 2;
        const u16* xb = xgb + (size_t)(t%3)*98304;
        #pragma unroll
        for (int c=0;c<4;++c){
          xr[c] = b2f(AT_LD(&xb[(size_t)rowc[c]*1536 + hcol]));
          xz[c] = b2f(AT_LD(&xb[(size_t)rowc[c]*1536 + 512 + hcol]));
          xn[c] = b2f(AT_LD(&xb[(size_t)rowc[c]*1536 + 1024 + hcol]));
        }
        stage_h256(h1d + (t&1)*32768, hs, tid);
        __syncthreads();
        u16* hwr = h1d + ((t&1)^1)*32768;
        #pragma unroll
        for (int c=0;c<4;++c){
          short8 af[16];
          #pragma unroll
          for (int kt=0;kt<16;++kt)
            af[kt] = *(const short8*)&hs[(c*16+lr)*512 + (((kt*4+lk) ^ (lr&7))<<3)];
          f32x4 ga = (f32x4){0.f,0.f,0.f,0.f};
          #pragma unroll
          for (int kt=0;kt<16;++kt) ga = MFMA16(af[kt], bw[kt], ga);
          f32x4 x = xpose4(ga, m);
          float hx = x[0] + ghmr[c];
          float rv = sigm(xr[c] + x[1] + g0[c]);
          float zv = sigm(xz[c] + x[2] + g1[c]);
          float nv = tanh_f(xn[c] + rv*(x[3] + g2[c]));
          float hv = zv*hx + (1.f - zv)*nv;
          u16 hb = f2bf(hv);
          AT_ST(&hwr[rowc[c]*512 + hcol], hb);
          Hall[(size_t)t*32768 + rowc[c]*512 + hcol] = hb;
        }
      }
    }
    if (p < 513){
      __syncthreads();
      if (tid == 0) AT_ST(&flags[blockIdx.x*32], (unsigned)(p+1));
      if (!role1 && p <= 510){
        const u16* xgn = XG0 + (size_t)(p+1)*98304;
        #pragma unroll
        for (int c=0;c<4;++c){
          const u16* q = xgn + (size_t)rowc[c]*1536;
          xr[c]=b2f(q[hcol]); xz[c]=b2f(q[512+hcol]); xn[c]=b2f(q[1024+hcol]);
        }
      }
      if (!role1){
        if (tid < 32){
          while (AT_LD(&flags[tid*32]) < (unsigned)(p+1)) {}
        } else if (tid < 64){
          if (p >= 1){ while (AT_LD(&flags[tid*32]) < (unsigned)p) {} }
        }
      } else {
        if (tid < 64){
          while (AT_LD(&flags[tid*32]) < (unsigned)(p+1)) {}
        }
      }
      __syncthreads();
    }
  }
}

// ghm{0,1}[b][j] = b{0,1}m[j] + sum_k lasth[b][k]*W{0,1}m[j][k]; also bf16 padded copy
__global__ void ghm_kernel(const float* __restrict__ lasth,
                           const float* __restrict__ W0m, const float* __restrict__ b0m,
                           const float* __restrict__ W1m, const float* __restrict__ b1m,
                           float* __restrict__ ghm0, float* __restrict__ ghm1,
                           u16* __restrict__ ghmP)
{
  int idx = blockIdx.x*256 + threadIdx.x;
  int chain = idx >> 15;
  int j = (idx >> 6) & 511;
  int b = idx & 63;
  const float* Wm = chain ? W1m : W0m;
  const float* bm = chain ? b1m : b0m;
  float s = 0.f;
  for (int k=0;k<512;++k) s += lasth[b*512 + k] * Wm[(size_t)j*1024 + k];
  float v = s + bm[j];
  (chain ? ghm1 : ghm0)[b*512 + j] = v;
  ghmP[(size_t)chain*65536 + b*512 + j] = f2bf(v);
}

extern "C" void kernel_launch(void* const* d_in, const int* in_sizes, int n_in,
                              void* d_out, int out_size, void* d_ws, size_t ws_size,
                              hipStream_t stream)
{
  const float* x    = (const float*)d_in[0];
  const float* Wih  = (const float*)d_in[1];
  const float* Whh  = (const float*)d_in[2];
  const float* bih  = (const float*)d_in[3];
  const float* bhh  = (const float*)d_in[4];
  const float* W0x  = (const float*)d_in[5];
  const float* b0x  = (const float*)d_in[6];
  const float* W0h  = (const float*)d_in[7];
  const float* b0h  = (const float*)d_in[8];
  const float* W0m  = (const float*)d_in[9];
  const float* b0m  = (const float*)d_in[10];
  const float* W1x  = (const float*)d_in[11];
  const float* b1x  = (const float*)d_in[12];
  const float* W1h  = (const float*)d_in[13];
  const float* b1h  = (const float*)d_in[14];
  const float* W1m  = (const float*)d_in[15];
  const float* b1m  = (const float*)d_in[16];
  const float* Wout = (const float*)d_in[17];
  const float* bout = (const float*)d_in[18];
  const float* Wdel = (const float*)d_in[19];
  const float* bdel = (const float*)d_in[20];
  const float* Wemb = (const float*)d_in[21];
  const float* bemb = (const float*)d_in[22];
  const int*   seqs = (const int*)d_in[23];
  float* out = (float*)d_out;

  const size_t OFF_DELTA = 17267712ull;
  const size_t OFF_EMB   = 17300416ull;
  const size_t OFF_LASTH = 148116416ull;

  uint8_t* ws = (uint8_t*)d_ws;
  size_t off = 0;
  auto alloc = [&](size_t bytes)->size_t{ size_t p = off; off += (bytes + 511) & ~(size_t)511; return p; };
  u16*   XGE  = (u16*)(ws + alloc(32768ull*1536*2));     // xg_enc; head aliases WmT before GEMM1a
  u16*   WmT0 = XGE;
  u16*   WmT1 = XGE + 262144;
  u16*   XG0  = (u16*)(ws + alloc(32768ull*1536*2));     // x2h0; Ob aliases head after decf
  u16*   Ob   = XG0;
  uint8_t* reg3 = ws + alloc(2ull*33554432);             // Xp (pre) aliases H1 (post)
  u16*   Xp   = (u16*)reg3;
  u16*   H1   = (u16*)reg3;
  u16*   Wc   = (u16*)(ws + alloc(3072ull*576*2));
  u16*   Whc  = (u16*)(ws + alloc(1536ull*512*2));
  u16*   W0hc = (u16*)(ws + alloc(1536ull*512*2));
  u16*   W1hc = (u16*)(ws + alloc(1536ull*512*2));
  u16*   W1xc = (u16*)(ws + alloc(1536ull*512*2));
  u16*   Wm0c = (u16*)(ws + alloc(512ull*512*2));
  u16*   Wm1c = (u16*)(ws + alloc(512ull*512*2));
  u16*   Wcp0 = (u16*)(ws + alloc(1536ull*512*2));
  u16*   Wcp1 = (u16*)(ws + alloc(1536ull*512*2));
  u16*   Woc  = (u16*)(ws + alloc(640ull*512*2));
  u16*   Wep  = (u16*)(ws + alloc(8ull*512*64*2));
  u16*   ghmP = (u16*)(ws + alloc(2ull*128*512*2));
  u16*   xgb  = (u16*)(ws + alloc(3ull*64*1536*2));      // xg1 exchange, triple buffered
  float* bc1  = (float*)(ws + alloc(3072*4));
  float* bc3  = (float*)(ws + alloc(640*4));
  float* bep  = (float*)(ws + alloc(8*512*4));
  float* bzero= (float*)(ws + alloc(512*4));
  float* ghm0 = (float*)(ws + alloc(64*512*4));
  float* ghm1 = (float*)(ws + alloc(64*512*4));
  float* ghW0 = (float*)(ws + alloc(64*1536*4));
  float* ghW1 = (float*)(ws + alloc(64*1536*4));
  size_t state_off = off;
  u16*   henc = (u16*)(ws + alloc(2*64*512*2));
  u16*   h0d  = (u16*)(ws + alloc(2*64*512*2));
  u16*   h1d  = (u16*)(ws + alloc(2*64*512*2));
  unsigned* bars = (unsigned*)(ws + alloc(16384));       // enc: bars, decf: bars+1024
  size_t state_bytes = off - state_off;
  if (ws_size < off) return;

  hipMemsetAsync(ws + state_off, 0, state_bytes, stream);
  hipMemsetAsync(Woc, 0, 640ull*512*2, stream);
  hipMemsetAsync(Wep, 0, 8ull*512*64*2, stream);
  hipMemsetAsync(ghmP, 0, 2ull*128*512*2, stream);
  hipMemsetAsync(bc3, 0, 640*4, stream);
  hipMemsetAsync(bzero, 0, 512*4, stream);

  hipMemcpyAsync(bc1,        bih,  1536*4, hipMemcpyDeviceToDevice, stream);
  hipMemcpyAsync(bc1 + 1536, b0x,  1536*4, hipMemcpyDeviceToDevice, stream);
  hipMemcpyAsync(bc3,        bout, 528*4,  hipMemcpyDeviceToDevice, stream);
  hipMemcpyAsync(bc3 + 528,  bdel, 4,      hipMemcpyDeviceToDevice, stream);

  auto CV = [&](const float* s, u16* d, int R, int sStride, int sOff, int Cd, int Ccopy){
    int total = R*Cd; int gb = (total + 255)/256;
    cvt_pad<<<dim3(gb), dim3(256), 0, stream>>>(s, d, R, sStride, sOff, Cd, Ccopy);
  };
  CV(x,    Xp, 32768, 528, 0, 576, 528);
  CV(Wih,  Wc,              1536, 528, 0, 576, 528);
  CV(W0x,  Wc + 1536ull*576,1536, 528, 0, 576, 528);
  CV(Whh,  Whc,  1536, 512, 0, 512, 512);
  CV(W0h,  W0hc, 1536, 512, 0, 512, 512);
  CV(W1h,  W1hc, 1536, 512, 0, 512, 512);
  CV(W1x,  W1xc, 1536, 512, 0, 512, 512);
  CV(W0m,  Wm0c, 512, 1024, 512, 512, 512);
  CV(W1m,  Wm1c, 512, 1024, 512, 512, 512);
  CV(Wout, Woc,              528, 512, 0, 512, 512);
  CV(Wdel, Woc + 528ull*512, 1,   512, 0, 512, 512);
  for (int e=0;e<8;++e) CV(Wemb + (size_t)e*32000, Wep + (size_t)e*32768, 500, 64, 0, 64, 64);
  {
    int gb = (8*512 + 255)/256;
    padf<<<dim3(gb), dim3(256), 0, stream>>>(bemb, bep, 8, 500, 512);
  }
  wmT_kernel<<<dim3(1024), dim3(256), 0, stream>>>(W0m, WmT0);
  wmT_kernel<<<dim3(1024), dim3(256), 0, stream>>>(W1m, WmT1);

  // Wcomp = Wh @ Wmh (bf16), before GEMM1a overwrites XGE (WmT alias)
  gemm_bt<<<dim3(12,4), dim3(256), 0, stream>>>(W0hc, 512, WmT0, 512, bzero,
      1536, 512, 512, 1, Wcp0, nullptr, nullptr, 512);
  gemm_bt<<<dim3(12,4), dim3(256), 0, stream>>>(W1hc, 512, WmT1, 512, bzero,
      1536, 512, 512, 1, Wcp1, nullptr, nullptr, 512);

  // GEMM1a: xg_enc = Xp @ Wih^T + bih (XGE half only)
  gemm_bt<<<dim3(256,12), dim3(256), 0, stream>>>(Xp, 576, Wc, 576, bc1,
      32768, 1536, 576, 0, XGE, nullptr, nullptr, 0);
  // encoder recurrence + overlapped XG0-half GEMM (blocks 16..3087)
  encg_kernel<<<dim3(16 + 3072), dim3(512), 0, stream>>>(Whc, bhh, XGE, seqs,
      henc, out + OFF_LASTH, bars + 0,
      Xp, Wc + 1536ull*576, bc1 + 1536, XG0);
  // ghm0/ghm1
  ghm_kernel<<<dim3(256), dim3(256), 0, stream>>>(out + OFF_LASTH, W0m, b0m, W1m, b1m,
      ghm0, ghm1, ghmP);
  // ghW{0,1} = ghm @ Wh^T + bh
  gemm_bt<<<dim3(1,12), dim3(256), 0, stream>>>(ghmP, 512, W0hc, 512, b0h,
      64, 1536, 512, 5, ghW0, nullptr, nullptr, 1536);
  gemm_bt<<<dim3(1,12), dim3(256), 0, stream>>>(ghmP + 65536, 512, W1hc, 512, b1h,
      64, 1536, 512, 5, ghW1, nullptr, nullptr, 1536);
  // fused decoder (64 WGs x 256 threads, r12-proven)
  decf_kernel<<<dim3(64), dim3(256), 0, stream>>>(
      Wm0c, Wcp0, ghm0, ghW0, W1xc, b1x,
      Wm1c, Wcp1, ghm1, ghW1,
      XG0, h0d, h1d, xgb, H1, bars + 1024);
  // GEMM3: out (f32) + pred_delta (f32) + Ob (bf16)
  gemm_bt<<<dim3(256,5), dim3(256), 0, stream>>>(H1, 512, Woc, 512, bc3,
      32768, 640, 512, 2, out, out + OFF_DELTA, Ob, 0);
  // GEMM4: emb logits
  gemm_bt<<<dim3(256,4,8), dim3(256), 0, stream>>>(Ob, 512, Wep, 64, bep,
      32704, 512, 64, 3, out + OFF_EMB, nullptr, nullptr, 0);
}